// Round 7
// baseline (4712.660 us; speedup 1.0000x reference)
//
#include <hip/hip_runtime.h>

#define HIST 50

__global__ void ue_naive(const int* nodes, const int* hitems,
                         const int* hrat, const int* hlen,
                         const float* u2e, const float* i2e, const float* r2e,
                         const float* w1w, const float* w1b,
                         const float* w2w, const float* w2b,
                         const float* a1w, const float* a1b,
                         const float* a2w, const float* a2b,
                         const float* a3w, const float* a3b,
                         float* out, int n_nodes)
{
    const int n = blockIdx.x;
    if (n >= n_nodes) return;
    const int j = threadIdx.x;          // 64 threads = 1 wave; j = output dim

    __shared__ float xs[128];           // current layer input
    __shared__ float ys[64];            // hidden activation
    __shared__ float us[64];            // user embedding
    __shared__ float osv[HIST * 64];    // per-neighbor o vectors
    __shared__ float red[64];           // reduction scratch
    __shared__ float sc[HIST];          // attention scores
    __shared__ float att[HIST];         // softmax weights

    const int node = nodes[n];
    const int hl   = hlen[n];

    us[j] = u2e[node * 64 + j];
    __syncthreads();

    for (int l = 0; l < hl; ++l) {      // l >= hl has softmax weight exactly 0: skip is exact
        const int item   = hitems[n * HIST + l];
        const int rating = hrat[n * HIST + l];

        // x = [p ; r]
        xs[j]      = i2e[(long)item * 64 + j];
        xs[64 + j] = r2e[(long)rating * 64 + j];
        __syncthreads();

        // y = relu(x @ w1.T + b1)
        float acc = w1b[j];
        for (int k = 0; k < 128; ++k) acc += xs[k] * w1w[j * 128 + k];
        ys[j] = fmaxf(acc, 0.f);
        __syncthreads();

        // o = relu(y @ w2.T + b2)
        acc = w2b[j];
        for (int k = 0; k < 64; ++k) acc += ys[k] * w2w[j * 64 + k];
        const float o = fmaxf(acc, 0.f);
        osv[l * 64 + j] = o;

        // a-input = [o ; u]
        xs[j]      = o;
        xs[64 + j] = us[j];
        __syncthreads();

        // a1 = relu([o;u] @ att1.T + ab1)
        acc = a1b[j];
        for (int k = 0; k < 128; ++k) acc += xs[k] * a1w[j * 128 + k];
        ys[j] = fmaxf(acc, 0.f);
        __syncthreads();

        // a2 = relu(a1 @ att2.T + ab2)
        acc = a2b[j];
        for (int k = 0; k < 64; ++k) acc += ys[k] * a2w[j * 64 + k];
        const float a2v = fmaxf(acc, 0.f);

        // score = a2 @ att3.T + ab3   (serial reduce by lane 0)
        red[j] = a2v * a3w[j];
        __syncthreads();
        if (j == 0) {
            float s = a3b[0];
            for (int k = 0; k < 64; ++k) s += red[k];
            sc[l] = s;
        }
        __syncthreads();
    }

    // softmax over valid l (serial by lane 0)
    if (j == 0) {
        float m = sc[0];
        for (int l = 1; l < hl; ++l) m = fmaxf(m, sc[l]);
        float se = 0.f;
        for (int l = 0; l < hl; ++l) { const float e = expf(sc[l] - m); att[l] = e; se += e; }
        const float inv = 1.f / se;
        for (int l = 0; l < hl; ++l) att[l] *= inv;
    }
    __syncthreads();

    // out = sum_l att[l] * o[l]
    float part = 0.f;
    for (int l = 0; l < hl; ++l) part += att[l] * osv[l * 64 + j];
    out[(long)n * 64 + j] = part;
}

extern "C" void kernel_launch(void* const* d_in, const int* in_sizes, int n_in,
                              void* d_out, int out_size, void* d_ws, size_t ws_size,
                              hipStream_t stream) {
    const int*   nodes  = (const int*)d_in[0];
    const int*   hitems = (const int*)d_in[1];
    const int*   hrat   = (const int*)d_in[2];
    const int*   hlenp  = (const int*)d_in[3];
    const float* u2e    = (const float*)d_in[4];
    const float* i2e    = (const float*)d_in[5];
    const float* r2e    = (const float*)d_in[6];
    const float* w1w    = (const float*)d_in[7];
    const float* w1b    = (const float*)d_in[8];
    const float* w2w    = (const float*)d_in[9];
    const float* w2b    = (const float*)d_in[10];
    const float* a1w    = (const float*)d_in[11];
    const float* a1b    = (const float*)d_in[12];
    const float* a2w    = (const float*)d_in[13];
    const float* a2b    = (const float*)d_in[14];
    const float* a3w    = (const float*)d_in[15];
    const float* a3b    = (const float*)d_in[16];
    float* out = (float*)d_out;

    const int n_nodes = in_sizes[0];
    ue_naive<<<dim3(n_nodes), dim3(64), 0, stream>>>(
        nodes, hitems, hrat, hlenp, u2e, i2e, r2e,
        w1w, w1b, w2w, w2b, a1w, a1b, a2w, a2b, a3w, a3b,
        out, n_nodes);
}